// Round 13
// baseline (1128.115 us; speedup 1.0000x reference)
//
#include <hip/hip_runtime.h>
#include <cstdint>
#include <cstddef>

// ---------------------------------------------------------------------------
// ShuffleWindowAttention, MI355X (gfx950)
// B=4, N=50176, C=512, WS=49, w=1024 windows/batch, NH=8, hd=64
// Pipeline (window-major intermediates):
//   prep_weights ; prep_x (fp32->bf16, token->window-major gather)
//   -> QKV GEMM (256^2, BK=32, 2 blocks/CU, R9 counted-vmcnt schedule)
//   -> windowed attention (vswz, conflict-free) -> proj GEMM (same template).
// R13 = R12 with the GEMM moved to BK=32 (LDS 64 KB -> 2 blocks/CU): same R9
// sync skeleton (counted vmcnt tile gate, drift phases, end-of-tile barrier),
// 16 K-tiles, 4 loads/thread/tile -> WAITV(1) gate.
// ---------------------------------------------------------------------------

typedef __bf16 bf16x8 __attribute__((ext_vector_type(8)));
typedef __bf16 bf16x4 __attribute__((ext_vector_type(4)));
typedef float  f32x4  __attribute__((ext_vector_type(4)));

#define MFMA_BF16(a, b, c) __builtin_amdgcn_mfma_f32_16x16x32_bf16((a), (b), (c), 0, 0, 0)

static __device__ __forceinline__ int swzi(int row, int col) {
  return col ^ ((row & 7) << 3);   // sP swizzle (128B rows)
}
// vT swizzle (attn): write banks spread across lanes, reads 2-way/free
static __device__ __forceinline__ int vswz(int n, int k) {
  return k ^ (((n ^ (n >> 3)) & 7) << 3);
}
// GEMM BK=32 tiles: 32-elem (64B) rows, 4 chunks of 8 elems; 2-way-free reads
static __device__ __forceinline__ int g4f(int row) {
  return (row ^ (row >> 2)) & 3;
}

typedef __attribute__((address_space(1))) const void gconst_t;
typedef __attribute__((address_space(3))) void lds_t;
static __device__ __forceinline__ void gload16(const void* g, void* l) {
  __builtin_amdgcn_global_load_lds((gconst_t*)g, (lds_t*)l, 16, 0, 0);
}

#define WAITV1()   asm volatile("s_waitcnt vmcnt(1)" ::: "memory")
#define WAITV0()   asm volatile("s_waitcnt vmcnt(0)" ::: "memory")

// window-major row -> token row
static __device__ __forceinline__ int wm2tok(int m) {
  const int b   = m / 50176;
  const int rem = m - b * 50176;
  const int wi  = rem / 49;
  const int s   = rem - wi * 49;
  return b * 50176 + s * 1024 + wi;
}

// ---------------------------------------------------------------------------
__global__ void prep_weights(const float* __restrict__ wqkv,
                             const float* __restrict__ bqkv,
                             const float* __restrict__ wproj,
                             __bf16* __restrict__ wqkv_bf,
                             __bf16* __restrict__ wproj_bf,
                             float* __restrict__ bq_s) {
  const int stride = gridDim.x * blockDim.x;
  const int t0 = blockIdx.x * blockDim.x + threadIdx.x;
  for (int i = t0; i < 1536 * 512; i += stride) {
    float v = wqkv[i];
    if (i < 512 * 512) v *= 0.125f;
    wqkv_bf[i] = (__bf16)v;
  }
  for (int i = t0; i < 512 * 512; i += stride) wproj_bf[i] = (__bf16)wproj[i];
  for (int i = t0; i < 1536; i += stride)      bq_s[i] = (i < 512 ? 0.125f : 1.0f) * bqkv[i];
}

// x: fp32 token-major [200704][512] -> bf16 WINDOW-MAJOR [200704][512]
__global__ void prep_x(const float* __restrict__ x, __bf16* __restrict__ xb) {
  const size_t total  = (size_t)200704 * 64;   // 8-elem groups
  const size_t stride = (size_t)gridDim.x * blockDim.x;
  for (size_t i = (size_t)blockIdx.x * blockDim.x + threadIdx.x; i < total; i += stride) {
    const int m  = (int)(i >> 6);              // window-major out row
    const int c8 = ((int)i & 63) * 8;
    const size_t t = (size_t)wm2tok(m);        // token-major src row
    const float4 a = *(const float4*)(x + t * 512 + c8);
    const float4 b = *(const float4*)(x + t * 512 + c8 + 4);
    bf16x8 v;
    v[0] = (__bf16)a.x; v[1] = (__bf16)a.y; v[2] = (__bf16)a.z; v[3] = (__bf16)a.w;
    v[4] = (__bf16)b.x; v[5] = (__bf16)b.y; v[6] = (__bf16)b.z; v[7] = (__bf16)b.w;
    *(bf16x8*)(xb + i * 8) = v;
  }
}

// ---------------------------------------------------------------------------
// 256x256-tile GEMM, BK=32, 16 K-tiles, LDS 64 KiB dbuf -> 2 blocks/CU.
// Per K-tile (R9 sync skeleton, counts adapted):
//   top:   [STAGE Ah0(t+1), 1 load] ; vmcnt(1) (4 tile-t loads forced done) ;
//          s_barrier ; sched_barrier
//   ph0:   LDB + LDA(mh0) ; MFMA ; stage Ah1+Bh0(t+1)   (drift, no barriers)
//   ph1:   stage Bh1(t+1) ; LDA(mh1) ; MFMA
//   end:   sched_barrier ; s_barrier   (all reads of buf retired)
// 4-chunk XOR swizzle: phys chunk p holds global chunk p ^ g4f(row);
// staging dest stays lane-linear, fragment reads 2-way (free).
// PERM_OUT: store rows permuted window-major -> token-major (proj output).
// ---------------------------------------------------------------------------
template<bool OUT_F32, bool PERM_OUT>
__launch_bounds__(512, 2)
__global__ void gemm256(const __bf16* __restrict__ Ab,   // [M][512]
                        const __bf16* __restrict__ Bw,   // [N][512]
                        const float* __restrict__ bias,  // [N]
                        void* __restrict__ Cv,
                        int Mtiles, int Ntiles) {
  __shared__ __align__(16) __bf16 sA[2][256 * 32];
  __shared__ __align__(16) __bf16 sB[2][256 * 32];

  const int tid  = threadIdx.x;
  const int lane = tid & 63;
  const int l15  = lane & 15;
  const int kgc  = (lane >> 4) & 3;     // k-chunk (8 elems) within 32-k tile
  const int r4   = kgc * 4;             // C/D row group
  const int wv   = tid >> 6;            // 0..7
  const int wm   = wv >> 2, wn = wv & 3;

  const int nwg = Mtiles * Ntiles;
  const int cpx = nwg >> 3;                       // nwg % 8 == 0
  const int wg  = (blockIdx.x & 7) * cpx + (blockIdx.x >> 3);
  const int mt  = wg / Ntiles;                    // M-outer: A-tile L2 reuse
  const int nt  = wg % Ntiles;
  const size_t m0 = (size_t)mt * 256;
  const int    n0 = nt * 256;

  // staging: thread covers row h*128 + (tid>>2), phys chunk tid&3,
  // global chunk pre-swizzled: (tid&3) ^ g4f(row)  (row tile-local)
  const int srow   = tid >> 2;                    // 0..127
  const int schunk = (tid & 3) ^ g4f(srow);       // g4f(h*128+srow)==g4f(srow)

  f32x4 acc[8][4];
  const f32x4 zf = {0.f, 0.f, 0.f, 0.f};
#pragma unroll
  for (int i = 0; i < 8; ++i)
#pragma unroll
    for (int j = 0; j < 4; ++j) acc[i][j] = zf;

  // stage one half-tile (1 x gload16): mat 0=A 1=B, half h (rows h*128..+127)
  auto STAGE_HALF = [&](int bufi, int kt, int mat, int h) {
    const size_t kof = (size_t)kt * 32 + schunk * 8;
    const __bf16* src = mat ? Bw : Ab;
    const size_t base0 = mat ? (size_t)n0 : m0;
    __bf16* dst = (mat ? &sB[bufi][0] : &sA[bufi][0]) + h * 4096 + tid * 8;
    gload16(src + (base0 + (size_t)(h * 128 + srow)) * 512 + kof, dst);
  };

  auto LDB = [&](int bufi, bf16x8* bfrag) {
#pragma unroll
    for (int n = 0; n < 4; ++n) {
      const int r = wn * 64 + n * 16 + l15;
      bfrag[n] = *(const bf16x8*)&sB[bufi][r * 32 + ((kgc ^ g4f(r)) * 8)];
    }
  };
  auto LDA = [&](int bufi, int mh, bf16x8* afrag) {
#pragma unroll
    for (int m2 = 0; m2 < 4; ++m2) {
      const int r = wm * 128 + mh * 64 + m2 * 16 + l15;
      afrag[m2] = *(const bf16x8*)&sA[bufi][r * 32 + ((kgc ^ g4f(r)) * 8)];
    }
  };
  auto MM = [&](int mh, const bf16x8* afrag, const bf16x8* bfrag) {
    __builtin_amdgcn_s_setprio(1);
#pragma unroll
    for (int m2 = 0; m2 < 4; ++m2)
#pragma unroll
      for (int n = 0; n < 4; ++n)
        acc[mh * 4 + m2][n] = MFMA_BF16(afrag[m2], bfrag[n], acc[mh * 4 + m2][n]);
    __builtin_amdgcn_s_setprio(0);
  };

  // prologue: all 4 half-tiles of K-tile 0 -> buf 0 (4 loads in flight)
  STAGE_HALF(0, 0, 0, 0); STAGE_HALF(0, 0, 0, 1);
  STAGE_HALF(0, 0, 1, 0); STAGE_HALF(0, 0, 1, 1);

  int buf = 0;
  for (int t = 0; t < 16; ++t) {
    const int nxt = buf ^ 1;
    // ---- tile top: counted wait + collective barrier ----
    if (t < 15) { STAGE_HALF(nxt, t + 1, 0, 0); WAITV1(); }
    else        { WAITV0(); }
    __builtin_amdgcn_s_barrier();
    __builtin_amdgcn_sched_barrier(0);

    bf16x8 b0[4], a[4];
    // phase 0: mh0
    LDB(buf, b0);
    LDA(buf, 0, a);
    MM(0, a, b0);
    if (t < 15) { STAGE_HALF(nxt, t + 1, 0, 1); STAGE_HALF(nxt, t + 1, 1, 0); }
    // phase 1: mh1
    if (t < 15) STAGE_HALF(nxt, t + 1, 1, 1);
    LDA(buf, 1, a);
    MM(1, a, b0);

    // end-of-tile barrier: all waves done reading buf
    __builtin_amdgcn_sched_barrier(0);
    __builtin_amdgcn_s_barrier();
    buf = nxt;
  }

  // ---- epilogue ----
  const int Nld = Ntiles * 256;
#pragma unroll
  for (int m = 0; m < 8; ++m) {
#pragma unroll
    for (int r = 0; r < 4; ++r) {
      const int row = (int)m0 + wm * 128 + m * 16 + r4 + r;   // window-major
      const size_t orow = PERM_OUT ? (size_t)wm2tok(row) : (size_t)row;
#pragma unroll
      for (int n = 0; n < 4; ++n) {
        const int col = n0 + wn * 64 + n * 16 + l15;
        const float v = acc[m][n][r] + bias[col];
        if (OUT_F32) ((float*)Cv)[orow * (size_t)Nld + col] = v;
        else         ((__bf16*)Cv)[orow * (size_t)Nld + col] = (__bf16)v;
      }
    }
  }
}

// ---------------------------------------------------------------------------
// Windowed attention: one block (8 waves) per window, wave = head.
// qkv WINDOW-MAJOR [blk*49 + s][1536] bf16 in;  O WINDOW-MAJOR [.][512] out.
// vT uses vswz (double-XOR) -> V-stage writes 8-way instead of 64-way.
// ---------------------------------------------------------------------------
__launch_bounds__(512)
__global__ void attn_win(const __bf16* __restrict__ qkv, __bf16* __restrict__ O) {
  __shared__ __align__(16) __bf16 vT[8 * 64 * 64];   // [h][n][vswz(n,k)]
  __shared__ __align__(16) __bf16 sP[8][16 * 64];    // per-wave P tile

  const int tid  = threadIdx.x;
  const int lane = tid & 63;
  const int h    = tid >> 6;                 // wave = head
  const int l15  = lane & 15;
  const int kg   = ((lane >> 4) & 3) * 8;
  const int r4   = ((lane >> 4) & 3) * 4;

  const size_t wbase = (size_t)blockIdx.x * 49;   // window-major row base

  const int MOFF[4] = {0, 16, 32, 33};
  const float NEG_INF = -__builtin_inff();

  // ---- issue q,k fragment loads early (overlap with V staging) ----
  bf16x8 aq[4][2], bk[4][2];
#pragma unroll
  for (int mt = 0; mt < 4; ++mt) {
    const size_t tok = wbase + (size_t)(MOFF[mt] + l15);
#pragma unroll
    for (int ks = 0; ks < 2; ++ks) {
      aq[mt][ks] = *(const bf16x8*)(qkv + tok * 1536 +       h * 64 + ks * 32 + kg);
      bk[mt][ks] = *(const bf16x8*)(qkv + tok * 1536 + 512 + h * 64 + ks * 32 + kg);
    }
  }

  // ---- zero vT pad rows k = 49..63 ----
  for (int i = tid; i < 8 * 64 * 16; i += 512) {
    const int k = 48 + (i & 15);
    if (k != 48) {
      const int n  = (i >> 4) & 63;
      const int hh = i >> 10;
      vT[hh * 4096 + n * 64 + vswz(n, k)] = (__bf16)0.0f;
    }
  }
  // ---- stage V transposed (+swizzled); reads fully contiguous ----
  for (int i = tid; i < 49 * 64; i += 512) {
    const int s  = i >> 6;
    const int c8 = (i & 63) * 8;
    bf16x8 v8 = *(const bf16x8*)(qkv + (wbase + s) * 1536 + 1024 + c8);
    const int hh = c8 >> 6;
#pragma unroll
    for (int j = 0; j < 8; ++j) {
      const int n = (c8 & 63) + j;
      vT[hh * 4096 + n * 64 + vswz(n, s)] = v8[j];
    }
  }
  __syncthreads();

  // ---- V fragments (2-way/free via vswz) ----
  bf16x8 bv[4][2];
#pragma unroll
  for (int ntv = 0; ntv < 4; ++ntv) {
    const int n = ntv * 16 + l15;
#pragma unroll
    for (int ks = 0; ks < 2; ++ks)
      bv[ntv][ks] = *(const bf16x8*)&vT[h * 4096 + n * 64 + vswz(n, ks * 32 + kg)];
  }

  // ---- S = q k^T ----
  f32x4 accS[4][4];
  const f32x4 zf = {0.f, 0.f, 0.f, 0.f};
#pragma unroll
  for (int m = 0; m < 4; ++m)
#pragma unroll
    for (int n = 0; n < 4; ++n) accS[m][n] = zf;
#pragma unroll
  for (int ks = 0; ks < 2; ++ks)
#pragma unroll
    for (int m = 0; m < 4; ++m)
#pragma unroll
      for (int n = 0; n < 4; ++n)
        accS[m][n] = MFMA_BF16(aq[m][ks], bk[n][ks], accS[m][n]);

  // ---- per row-tile: softmax -> P (LDS) -> PV -> store O ----
#pragma unroll
  for (int mt = 0; mt < 4; ++mt) {
#pragma unroll
    for (int r = 0; r < 4; ++r) {
      const int prow = r4 + r;
      const float sv0 = accS[mt][0][r];
      const float sv1 = accS[mt][1][r];
      const float sv2 = accS[mt][2][r];
      const float sv3 = (l15 == 15) ? accS[mt][3][r] : NEG_INF;
      float mx = fmaxf(fmaxf(sv0, sv1), fmaxf(sv2, sv3));
      mx = fmaxf(mx, __shfl_xor(mx, 1));
      mx = fmaxf(mx, __shfl_xor(mx, 2));
      mx = fmaxf(mx, __shfl_xor(mx, 4));
      mx = fmaxf(mx, __shfl_xor(mx, 8));
      const float e0 = __expf(sv0 - mx);
      const float e1 = __expf(sv1 - mx);
      const float e2 = __expf(sv2 - mx);
      const float e3 = __expf(sv3 - mx);      // 0 for masked lanes
      float sum = e0 + e1 + e2 + e3;
      sum += __shfl_xor(sum, 1);
      sum += __shfl_xor(sum, 2);
      sum += __shfl_xor(sum, 4);
      sum += __shfl_xor(sum, 8);
      const float inv = 1.0f / sum;
      sP[h][prow * 64 + swzi(prow, 0  + l15)] = (__bf16)(e0 * inv);
      sP[h][prow * 64 + swzi(prow, 16 + l15)] = (__bf16)(e1 * inv);
      sP[h][prow * 64 + swzi(prow, 32 + l15)] = (__bf16)(e2 * inv);
      if (l15 == 15) sP[h][prow * 64 + swzi(prow, 48)] = (__bf16)(e3 * inv);
      if (l15 < 15)  sP[h][prow * 64 + swzi(prow, 49 + l15)] = (__bf16)0.0f;
    }
    bf16x8 ap[2];
#pragma unroll
    for (int ks = 0; ks < 2; ++ks)
      ap[ks] = *(const bf16x8*)&sP[h][l15 * 64 + swzi(l15, ks * 32 + kg)];
    f32x4 accO[4];
#pragma unroll
    for (int n = 0; n < 4; ++n) accO[n] = zf;
#pragma unroll
    for (int ks = 0; ks < 2; ++ks)
#pragma unroll
      for (int n = 0; n < 4; ++n)
        accO[n] = MFMA_BF16(ap[ks], bv[n][ks], accO[n]);
#pragma unroll
    for (int n = 0; n < 4; ++n) {
#pragma unroll
      for (int r = 0; r < 4; ++r) {
        const int row = MOFF[mt] + r4 + r;
        O[(wbase + row) * 512 + h * 64 + n * 16 + l15] = (__bf16)accO[n][r];
      }
    }
  }
}

// ===========================================================================
// Fallback: round-1 fused kernel (used only if ws_size is too small).
// ===========================================================================
__launch_bounds__(256, 2)
__global__ void swin_attn_fused(const float* __restrict__ x,
                                const __bf16* __restrict__ wqkv_bf,
                                const float* __restrict__ bq_s,
                                const __bf16* __restrict__ wproj_bf,
                                const float* __restrict__ bproj,
                                float* __restrict__ out) {
  __shared__ __align__(16) __bf16 s_xw[49 * 512];
  __shared__ __align__(16) __bf16 s_q [49 * 64];
  __shared__ __align__(16) __bf16 s_k [49 * 64];
  __shared__ __align__(16) __bf16 s_vT[64 * 64];
  __shared__ __align__(16) __bf16 s_p [49 * 64];

  const int tid  = threadIdx.x;
  const int lane = tid & 63;
  const int wv   = tid >> 6;
  const int l15  = lane & 15;
  const int kg   = (lane >> 4) * 8;
  const int r4   = (lane >> 4) * 4;
  const int blk = blockIdx.x;
  const int b   = blk >> 10;
  const int wi  = blk & 1023;
  const int MOFF[4] = {0, 16, 32, 33};
  const float NEG_INF = -__builtin_inff();

  for (int i = tid; i < 64 * 64; i += 256) s_vT[i] = (__bf16)0.0f;
  const float* xwin = x + ((size_t)b * 50176 + (size_t)wi) * 512;
  for (int idx = tid; idx < 49 * 128; idx += 256) {
    const int row = idx >> 7;
    const int c4  = (idx & 127) * 4;
    const float4 v = *(const float4*)(xwin + (size_t)row * (1024 * 512) + c4);
    bf16x4 t;
    t.x = (__bf16)v.x; t.y = (__bf16)v.y; t.z = (__bf16)v.z; t.w = (__bf16)v.w;
    *(bf16x4*)&s_xw[row * 512 + swzi(row, c4)] = t;
  }
  f32x4 accF[4][8];
  const f32x4 zf = {0.f, 0.f, 0.f, 0.f};
#pragma unroll
  for (int m = 0; m < 4; ++m)
#pragma unroll
    for (int n = 0; n < 8; ++n) accF[m][n] = zf;
  __syncthreads();

  for (int h = 0; h < 8; ++h) {
    f32x4 accA[4][3];
#pragma unroll
    for (int m = 0; m < 4; ++m)
#pragma unroll
      for (int n = 0; n < 3; ++n) accA[m][n] = zf;
    const __bf16* pB[3];
    float biasv[3];
#pragma unroll
    for (int nt = 0; nt < 3; ++nt) {
      const int c  = wv * 48 + nt * 16 + l15;
      const int wr = (c < 64) ? (h * 64 + c)
                   : (c < 128) ? (512 + h * 64 + (c - 64))
                               : (1024 + h * 64 + (c - 128));
      pB[nt]    = wqkv_bf + (size_t)wr * 512 + kg;
      biasv[nt] = bq_s[wr];
    }
#pragma unroll
    for (int ks = 0; ks < 16; ++ks) {
      bf16x8 a[4], bb[3];
#pragma unroll
      for (int mt = 0; mt < 4; ++mt) {
        const int row = MOFF[mt] + l15;
        a[mt] = *(const bf16x8*)&s_xw[row * 512 + swzi(row, ks * 32 + kg)];
      }
#pragma unroll
      for (int nt = 0; nt < 3; ++nt) bb[nt] = *(const bf16x8*)(pB[nt] + ks * 32);
#pragma unroll
      for (int mt = 0; mt < 4; ++mt)
#pragma unroll
        for (int nt = 0; nt < 3; ++nt)
          accA[mt][nt] = MFMA_BF16(a[mt], bb[nt], accA[mt][nt]);
    }
#pragma unroll
    for (int nt = 0; nt < 3; ++nt) {
      const int c = wv * 48 + nt * 16 + l15;
#pragma unroll
      for (int mt = 0; mt < 4; ++mt) {
#pragma unroll
        for (int r = 0; r < 4; ++r) {
          const int row = MOFF[mt] + r4 + r;
          const __bf16 bvv = (__bf16)(accA[mt][nt][r] + biasv[nt]);
          if (c < 64)       s_q[row * 64 + swzi(row, c)] = bvv;
          else if (c < 128) s_k[row * 64 + swzi(row, c - 64)] = bvv;
          else {
            const int vr = c - 128;
            s_vT[vr * 64 + swzi(vr, row)] = bvv;
          }
        }
      }
    }
    __syncthreads();

    const int R = MOFF[wv];
    bf16x8 aq[2], bkf[4][2];
#pragma unroll
    for (int ks2 = 0; ks2 < 2; ++ks2) {
      const int row = R + l15;
      aq[ks2] = *(const bf16x8*)&s_q[row * 64 + swzi(row, ks2 * 32 + kg)];
    }
#pragma unroll
    for (int nt = 0; nt < 4; ++nt) {
      const int row = MOFF[nt] + l15;
#pragma unroll
      for (int ks2 = 0; ks2 < 2; ++ks2)
        bkf[nt][ks2] = *(const bf16x8*)&s_k[row * 64 + swzi(row, ks2 * 32 + kg)];
    }
    f32x4 accS[4];
#pragma unroll
    for (int n = 0; n < 4; ++n) accS[n] = zf;
#pragma unroll
    for (int ks2 = 0; ks2 < 2; ++ks2)
#pragma unroll
      for (int nt = 0; nt < 4; ++nt)
        accS[nt] = MFMA_BF16(aq[ks2], bkf[nt][ks2], accS[nt]);
#pragma unroll
    for (int r = 0; r < 4; ++r) {
      const int row = R + r4 + r;
      const float sv0 = accS[0][r];
      const float sv1 = accS[1][r];
      const float sv2 = accS[2][r];
      const float sv3 = (l15 == 15) ? accS[3][r] : NEG_INF;
      float m = fmaxf(fmaxf(sv0, sv1), fmaxf(sv2, sv3));
      m = fmaxf(m, __shfl_xor(m, 1));
      m = fmaxf(m, __shfl_xor(m, 2));
      m = fmaxf(m, __shfl_xor(m, 4));
      m = fmaxf(m, __shfl_xor(m, 8));
      const float e0 = __expf(sv0 - m);
      const float e1 = __expf(sv1 - m);
      const float e2 = __expf(sv2 - m);
      const float e3 = __expf(sv3 - m);
      float s = e0 + e1 + e2 + e3;
      s += __shfl_xor(s, 1);
      s += __shfl_xor(s, 2);
      s += __shfl_xor(s, 4);
      s += __shfl_xor(s, 8);
      const float inv = 1.0f / s;
      s_p[row * 64 + swzi(row, 0  + l15)] = (__bf16)(e0 * inv);
      s_p[row * 64 + swzi(row, 16 + l15)] = (__bf16)(e1 * inv);
      s_p[row * 64 + swzi(row, 32 + l15)] = (__bf16)(e2 * inv);
      if (l15 == 15) s_p[row * 64 + swzi(row, 48)] = (__bf16)(e3 * inv);
      if (l15 < 15)  s_p[row * 64 + swzi(row, 49 + l15)] = (__bf16)0.0f;
    }
    bf16x8 ap[2], bv2[4][2];
#pragma unroll
    for (int ks2 = 0; ks2 < 2; ++ks2) {
      const int row = R + l15;
      ap[ks2] = *(const bf16x8*)&s_p[row * 64 + swzi(row, ks2 * 32 + kg)];
    }
#pragma unroll
    for (int nt = 0; nt < 4; ++nt) {
      const int row = nt * 16 + l15;
#pragma unroll
      for (int ks2 = 0; ks2 < 2; ++ks2)
        bv2[nt][ks2] = *(const bf16x8*)&s_vT[row * 64 + swzi(row, ks2 * 32 + kg)];
    }
    __syncthreads();
    f32x4 accO[4];
#pragma unroll
    for (int n = 0; n < 4; ++n) accO[n] = zf;
#pragma unroll
    for (int ks2 = 0; ks2 < 2; ++ks2)
#pragma unroll
      for (int nt = 0; nt < 4; ++nt)
        accO[nt] = MFMA_BF16(ap[ks2], bv2[nt][ks2], accO[nt]);
#pragma unroll
    for (int nt = 0; nt < 4; ++nt) {
#pragma unroll
      for (int r = 0; r < 4; ++r) {
        const int row = R + r4 + r;
        s_p[row * 64 + swzi(row, nt * 16 + l15)] = (__bf16)accO[nt][r];
      }
    }
    __syncthreads();
#pragma unroll
    for (int ks2 = 0; ks2 < 2; ++ks2) {
      bf16x8 ao[4], bw[8];
#pragma unroll
      for (int mt = 0; mt < 4; ++mt) {
        const int row = MOFF[mt] + l15;
        ao[mt] = *(const bf16x8*)&s_p[row * 64 + swzi(row, ks2 * 32 + kg)];
      }
#pragma unroll
      for (int nt = 0; nt < 8; ++nt) {
        const int cc = wv * 128 + nt * 16 + l15;
        bw[nt] = *(const bf16x8*)(wproj_bf + (size_t)cc * 512 + h * 64 + ks2 * 32 + kg);
      }
#pragma unroll
      for (int mt = 0; mt < 4; ++mt)
#pragma unroll
        for (int nt = 0; nt < 8; ++nt)
          accF[mt][nt] = MFMA_BF16(ao[mt], bw[nt], accF[mt][nt]);
    }
  }
#pragma unroll
  for (int nt = 0; nt < 8; ++nt) {
    const int cc = wv * 128 + nt * 16 + l15;
    const float bp = bproj[cc];
#pragma unroll
    for (int mt = 0; mt < 4; ++mt) {
#pragma unroll
      for (int r = 0; r < 4; ++r) {
        const int row = MOFF[mt] + r4 + r;
        if (mt < 3 || (r4 + r) == 15) {
          out[((size_t)b * 50176 + (size_t)row * 1024 + (size_t)wi) * 512 + cc] =
              accF[mt][nt][r] + bp;
        }
      }
    }
  }
}

// ---------------------------------------------------------------------------
extern "C" void kernel_launch(void* const* d_in, const int* in_sizes, int n_in,
                              void* d_out, int out_size, void* d_ws, size_t ws_size,
                              hipStream_t stream) {
  const float* x      = (const float*)d_in[0];
  const float* w_qkv  = (const float*)d_in[1];
  const float* b_qkv  = (const float*)d_in[2];
  const float* w_proj = (const float*)d_in[3];
  const float* b_proj = (const float*)d_in[4];
  float* outp = (float*)d_out;

  const size_t QKV_E = (size_t)200704 * 1536;
  const size_t O_E   = (size_t)200704 * 512;
  const size_t NEED  = (QKV_E + O_E + 786432 + 262144) * 2 + 1536 * 4;

  if (ws_size >= NEED) {
    __bf16* qkv      = (__bf16*)d_ws;
    __bf16* Obuf     = qkv + QKV_E;      // holds x_bf16 first, then attn output
    __bf16* wqkv_bf  = Obuf + O_E;
    __bf16* wproj_bf = wqkv_bf + 786432;
    float*  bq_s     = (float*)(wproj_bf + 262144);

    prep_weights<<<512, 256, 0, stream>>>(w_qkv, b_qkv, w_proj, wqkv_bf, wproj_bf, bq_s);
    prep_x<<<2048, 256, 0, stream>>>(x, Obuf);       // x -> bf16, window-major
    // QKV: M=200704 (784 tiles), N=1536 (6 tiles)
    gemm256<false, false><<<784 * 6, 512, 0, stream>>>(Obuf, wqkv_bf, bq_s, qkv, 784, 6);
    attn_win<<<4096, 512, 0, stream>>>(qkv, Obuf);   // overwrites x_bf16
    // proj: M=200704 (784 tiles), N=512 (2 tiles); permuted store to token-major
    gemm256<true, true><<<784 * 2, 512, 0, stream>>>(Obuf, wproj_bf, b_proj, outp, 784, 2);
  } else {
    __bf16* wqkv_bf  = (__bf16*)d_ws;
    __bf16* wproj_bf = wqkv_bf + 1536 * 512;
    float*  bq_s     = (float*)(wproj_bf + 512 * 512);
    prep_weights<<<1024, 256, 0, stream>>>(w_qkv, b_qkv, w_proj, wqkv_bf, wproj_bf, bq_s);
    swin_attn_fused<<<4096, 256, 0, stream>>>(x, wqkv_bf, bq_s, wproj_bf, b_proj, outp);
  }
}

// Round 14
// 981.931 us; speedup vs baseline: 1.1489x; 1.1489x over previous
//
#include <hip/hip_runtime.h>
#include <cstdint>
#include <cstddef>

// ---------------------------------------------------------------------------
// ShuffleWindowAttention, MI355X (gfx950)
// B=4, N=50176, C=512, WS=49, w=1024 windows/batch, NH=8, hd=64
// Pipeline (window-major intermediates):
//   prep_all (weights->bf16 + x fp32->bf16 window-major gather, one kernel)
//   -> QKV GEMM (256^2, BK=64, R9 counted-vmcnt schedule)
//   -> windowed attention (vswz, conflict-free) -> proj GEMM (same template).
// R14 = R12 verbatim (best verified: 981 us) + prep kernels merged.
// GEMM-schedule ledger: R5 456 | R6 524 | R9 417* | R10 487 | R13 520
//   -> R9 form final (occupancy register-bound at 2 waves/SIMD: 128 AGPR acc).
// ---------------------------------------------------------------------------

typedef __bf16 bf16x8 __attribute__((ext_vector_type(8)));
typedef __bf16 bf16x4 __attribute__((ext_vector_type(4)));
typedef float  f32x4  __attribute__((ext_vector_type(4)));

#define MFMA_BF16(a, b, c) __builtin_amdgcn_mfma_f32_16x16x32_bf16((a), (b), (c), 0, 0, 0)

static __device__ __forceinline__ int swzi(int row, int col) {
  return col ^ ((row & 7) << 3);   // sP swizzle (128B rows)
}
static __device__ __forceinline__ int vswz(int n, int k) {
  return k ^ (((n ^ (n >> 3)) & 7) << 3);
}

typedef __attribute__((address_space(1))) const void gconst_t;
typedef __attribute__((address_space(3))) void lds_t;
static __device__ __forceinline__ void gload16(const void* g, void* l) {
  __builtin_amdgcn_global_load_lds((gconst_t*)g, (lds_t*)l, 16, 0, 0);
}

#define WAITV2()   asm volatile("s_waitcnt vmcnt(2)" ::: "memory")
#define WAITV0()   asm volatile("s_waitcnt vmcnt(0)" ::: "memory")

// window-major row -> token row
static __device__ __forceinline__ int wm2tok(int m) {
  const int b   = m / 50176;
  const int rem = m - b * 50176;
  const int wi  = rem / 49;
  const int s   = rem - wi * 49;
  return b * 50176 + s * 1024 + wi;
}

// ---------------------------------------------------------------------------
// Weight prep: fp32 -> bf16, fold 0.125 attention scale into the Q block.
// ---------------------------------------------------------------------------
__global__ void prep_weights(const float* __restrict__ wqkv,
                             const float* __restrict__ bqkv,
                             const float* __restrict__ wproj,
                             __bf16* __restrict__ wqkv_bf,
                             __bf16* __restrict__ wproj_bf,
                             float* __restrict__ bq_s) {
  const int stride = gridDim.x * blockDim.x;
  const int t0 = blockIdx.x * blockDim.x + threadIdx.x;
  for (int i = t0; i < 1536 * 512; i += stride) {
    float v = wqkv[i];
    if (i < 512 * 512) v *= 0.125f;
    wqkv_bf[i] = (__bf16)v;
  }
  for (int i = t0; i < 512 * 512; i += stride) wproj_bf[i] = (__bf16)wproj[i];
  for (int i = t0; i < 1536; i += stride)      bq_s[i] = (i < 512 ? 0.125f : 1.0f) * bqkv[i];
}

// Combined prep: weights AND x gather/convert (main path, one launch).
__global__ void prep_all(const float* __restrict__ x,
                         const float* __restrict__ wqkv,
                         const float* __restrict__ bqkv,
                         const float* __restrict__ wproj,
                         __bf16* __restrict__ xb,
                         __bf16* __restrict__ wqkv_bf,
                         __bf16* __restrict__ wproj_bf,
                         float* __restrict__ bq_s) {
  const size_t gstride = (size_t)gridDim.x * blockDim.x;
  const size_t g0 = (size_t)blockIdx.x * blockDim.x + threadIdx.x;

  for (size_t i = g0; i < 1536 * 512; i += gstride) {
    float v = wqkv[i];
    if (i < 512 * 512) v *= 0.125f;
    wqkv_bf[i] = (__bf16)v;
  }
  for (size_t i = g0; i < 512 * 512; i += gstride) wproj_bf[i] = (__bf16)wproj[i];
  for (size_t i = g0; i < 1536; i += gstride)
    bq_s[i] = (i < 512 ? 0.125f : 1.0f) * bqkv[i];

  const size_t total = (size_t)200704 * 64;
  for (size_t i = g0; i < total; i += gstride) {
    const int m  = (int)(i >> 6);
    const int c8 = ((int)i & 63) * 8;
    const size_t t = (size_t)wm2tok(m);
    const float4 a = *(const float4*)(x + t * 512 + c8);
    const float4 b = *(const float4*)(x + t * 512 + c8 + 4);
    bf16x8 v;
    v[0] = (__bf16)a.x; v[1] = (__bf16)a.y; v[2] = (__bf16)a.z; v[3] = (__bf16)a.w;
    v[4] = (__bf16)b.x; v[5] = (__bf16)b.y; v[6] = (__bf16)b.z; v[7] = (__bf16)b.w;
    *(bf16x8*)(xb + i * 8) = v;
  }
}

// ---------------------------------------------------------------------------
// 256x256-tile GEMM (R9/R12 schedule, verbatim): counted WAITV(2) tile gate,
// staggered half-tile staging through drift phases, end-of-tile barrier.
// ---------------------------------------------------------------------------
template<bool OUT_F32, bool PERM_OUT>
__launch_bounds__(512, 2)
__global__ void gemm256(const __bf16* __restrict__ Ab,   // [M][512]
                        const __bf16* __restrict__ Bw,   // [N][512]
                        const float* __restrict__ bias,  // [N]
                        void* __restrict__ Cv,
                        int Mtiles, int Ntiles) {
  __shared__ __align__(16) __bf16 sA[2][256 * 64];
  __shared__ __align__(16) __bf16 sB[2][256 * 64];

  const int tid  = threadIdx.x;
  const int lane = tid & 63;
  const int l15  = lane & 15;
  const int kgc  = (lane >> 4) & 3;
  const int r4   = kgc * 4;
  const int wv   = tid >> 6;
  const int wm   = wv >> 2, wn = wv & 3;

  const int nwg = Mtiles * Ntiles;
  const int cpx = nwg >> 3;
  const int wg  = (blockIdx.x & 7) * cpx + (blockIdx.x >> 3);
  const int mt  = wg / Ntiles;
  const int nt  = wg % Ntiles;
  const size_t m0 = (size_t)mt * 256;
  const int    n0 = nt * 256;

  const int srow   = tid >> 3;
  const int schunk = (tid & 7) ^ (srow & 7);

  f32x4 acc[8][4];
  const f32x4 zf = {0.f, 0.f, 0.f, 0.f};
#pragma unroll
  for (int i = 0; i < 8; ++i)
#pragma unroll
    for (int j = 0; j < 4; ++j) acc[i][j] = zf;

  auto STAGE_HALF = [&](int bufi, int kt, int mat, int h) {
    const size_t kof = (size_t)kt * 64 + schunk * 8;
    const __bf16* src = mat ? Bw : Ab;
    const size_t base0 = mat ? (size_t)n0 : m0;
    __bf16* dst = (mat ? &sB[bufi][0] : &sA[bufi][0]) + h * 8192 + tid * 8;
#pragma unroll
    for (int j = 0; j < 2; ++j)
      gload16(src + (base0 + (size_t)(h * 128 + j * 64 + srow)) * 512 + kof,
              dst + j * 4096);
  };

  auto LDB = [&](int bufi, int ks, bf16x8* bfrag) {
#pragma unroll
    for (int n = 0; n < 4; ++n) {
      const int r = wn * 64 + n * 16 + l15;
      bfrag[n] = *(const bf16x8*)&sB[bufi][r * 64 + (((ks * 4 + kgc) ^ (r & 7)) * 8)];
    }
  };
  auto LDA = [&](int bufi, int mh, int ks, bf16x8* afrag) {
#pragma unroll
    for (int m2 = 0; m2 < 4; ++m2) {
      const int r = wm * 128 + mh * 64 + m2 * 16 + l15;
      afrag[m2] = *(const bf16x8*)&sA[bufi][r * 64 + (((ks * 4 + kgc) ^ (r & 7)) * 8)];
    }
  };
  auto MM = [&](int mh, const bf16x8* afrag, const bf16x8* bfrag) {
    __builtin_amdgcn_s_setprio(1);
#pragma unroll
    for (int m2 = 0; m2 < 4; ++m2)
#pragma unroll
      for (int n = 0; n < 4; ++n)
        acc[mh * 4 + m2][n] = MFMA_BF16(afrag[m2], bfrag[n], acc[mh * 4 + m2][n]);
    __builtin_amdgcn_s_setprio(0);
  };

  STAGE_HALF(0, 0, 0, 0); STAGE_HALF(0, 0, 0, 1);
  STAGE_HALF(0, 0, 1, 0); STAGE_HALF(0, 0, 1, 1);

  int buf = 0;
  for (int t = 0; t < 8; ++t) {
    const int nxt = buf ^ 1;
    if (t < 7) { STAGE_HALF(nxt, t + 1, 0, 0); WAITV2(); }
    else       { WAITV0(); }
    __builtin_amdgcn_s_barrier();
    __builtin_amdgcn_sched_barrier(0);

    bf16x8 b0[4], b1[4], a[4];
    LDB(buf, 0, b0);
    LDA(buf, 0, 0, a);
    MM(0, a, b0);
    if (t < 7) STAGE_HALF(nxt, t + 1, 0, 1);
    LDA(buf, 1, 0, a);
    MM(1, a, b0);
    if (t < 7) STAGE_HALF(nxt, t + 1, 1, 0);
    LDB(buf, 1, b1);
    LDA(buf, 0, 1, a);
    MM(0, a, b1);
    if (t < 7) STAGE_HALF(nxt, t + 1, 1, 1);
    LDA(buf, 1, 1, a);
    MM(1, a, b1);

    __builtin_amdgcn_sched_barrier(0);
    __builtin_amdgcn_s_barrier();
    buf = nxt;
  }

  const int Nld = Ntiles * 256;
#pragma unroll
  for (int m = 0; m < 8; ++m) {
#pragma unroll
    for (int r = 0; r < 4; ++r) {
      const int row = (int)m0 + wm * 128 + m * 16 + r4 + r;
      const size_t orow = PERM_OUT ? (size_t)wm2tok(row) : (size_t)row;
#pragma unroll
      for (int n = 0; n < 4; ++n) {
        const int col = n0 + wn * 64 + n * 16 + l15;
        const float v = acc[m][n][r] + bias[col];
        if (OUT_F32) ((float*)Cv)[orow * (size_t)Nld + col] = v;
        else         ((__bf16*)Cv)[orow * (size_t)Nld + col] = (__bf16)v;
      }
    }
  }
}

// ---------------------------------------------------------------------------
// Windowed attention (R12 verbatim): vswz double-XOR, conflict-free.
// ---------------------------------------------------------------------------
__launch_bounds__(512)
__global__ void attn_win(const __bf16* __restrict__ qkv, __bf16* __restrict__ O) {
  __shared__ __align__(16) __bf16 vT[8 * 64 * 64];
  __shared__ __align__(16) __bf16 sP[8][16 * 64];

  const int tid  = threadIdx.x;
  const int lane = tid & 63;
  const int h    = tid >> 6;
  const int l15  = lane & 15;
  const int kg   = ((lane >> 4) & 3) * 8;
  const int r4   = ((lane >> 4) & 3) * 4;

  const size_t wbase = (size_t)blockIdx.x * 49;

  const int MOFF[4] = {0, 16, 32, 33};
  const float NEG_INF = -__builtin_inff();

  bf16x8 aq[4][2], bk[4][2];
#pragma unroll
  for (int mt = 0; mt < 4; ++mt) {
    const size_t tok = wbase + (size_t)(MOFF[mt] + l15);
#pragma unroll
    for (int ks = 0; ks < 2; ++ks) {
      aq[mt][ks] = *(const bf16x8*)(qkv + tok * 1536 +       h * 64 + ks * 32 + kg);
      bk[mt][ks] = *(const bf16x8*)(qkv + tok * 1536 + 512 + h * 64 + ks * 32 + kg);
    }
  }

  for (int i = tid; i < 8 * 64 * 16; i += 512) {
    const int k = 48 + (i & 15);
    if (k != 48) {
      const int n  = (i >> 4) & 63;
      const int hh = i >> 10;
      vT[hh * 4096 + n * 64 + vswz(n, k)] = (__bf16)0.0f;
    }
  }
  for (int i = tid; i < 49 * 64; i += 512) {
    const int s  = i >> 6;
    const int c8 = (i & 63) * 8;
    bf16x8 v8 = *(const bf16x8*)(qkv + (wbase + s) * 1536 + 1024 + c8);
    const int hh = c8 >> 6;
#pragma unroll
    for (int j = 0; j < 8; ++j) {
      const int n = (c8 & 63) + j;
      vT[hh * 4096 + n * 64 + vswz(n, s)] = v8[j];
    }
  }
  __syncthreads();

  bf16x8 bv[4][2];
#pragma unroll
  for (int ntv = 0; ntv < 4; ++ntv) {
    const int n = ntv * 16 + l15;
#pragma unroll
    for (int ks = 0; ks < 2; ++ks)
      bv[ntv][ks] = *(const bf16x8*)&vT[h * 4096 + n * 64 + vswz(n, ks * 32 + kg)];
  }

  f32x4 accS[4][4];
  const f32x4 zf = {0.f, 0.f, 0.f, 0.f};
#pragma unroll
  for (int m = 0; m < 4; ++m)
#pragma unroll
    for (int n = 0; n < 4; ++n) accS[m][n] = zf;
#pragma unroll
  for (int ks = 0; ks < 2; ++ks)
#pragma unroll
    for (int m = 0; m < 4; ++m)
#pragma unroll
      for (int n = 0; n < 4; ++n)
        accS[m][n] = MFMA_BF16(aq[m][ks], bk[n][ks], accS[m][n]);

#pragma unroll
  for (int mt = 0; mt < 4; ++mt) {
#pragma unroll
    for (int r = 0; r < 4; ++r) {
      const int prow = r4 + r;
      const float sv0 = accS[mt][0][r];
      const float sv1 = accS[mt][1][r];
      const float sv2 = accS[mt][2][r];
      const float sv3 = (l15 == 15) ? accS[mt][3][r] : NEG_INF;
      float mx = fmaxf(fmaxf(sv0, sv1), fmaxf(sv2, sv3));
      mx = fmaxf(mx, __shfl_xor(mx, 1));
      mx = fmaxf(mx, __shfl_xor(mx, 2));
      mx = fmaxf(mx, __shfl_xor(mx, 4));
      mx = fmaxf(mx, __shfl_xor(mx, 8));
      const float e0 = __expf(sv0 - mx);
      const float e1 = __expf(sv1 - mx);
      const float e2 = __expf(sv2 - mx);
      const float e3 = __expf(sv3 - mx);
      float sum = e0 + e1 + e2 + e3;
      sum += __shfl_xor(sum, 1);
      sum += __shfl_xor(sum, 2);
      sum += __shfl_xor(sum, 4);
      sum += __shfl_xor(sum, 8);
      const float inv = 1.0f / sum;
      sP[h][prow * 64 + swzi(prow, 0  + l15)] = (__bf16)(e0 * inv);
      sP[h][prow * 64 + swzi(prow, 16 + l15)] = (__bf16)(e1 * inv);
      sP[h][prow * 64 + swzi(prow, 32 + l15)] = (__bf16)(e2 * inv);
      if (l15 == 15) sP[h][prow * 64 + swzi(prow, 48)] = (__bf16)(e3 * inv);
      if (l15 < 15)  sP[h][prow * 64 + swzi(prow, 49 + l15)] = (__bf16)0.0f;
    }
    bf16x8 ap[2];
#pragma unroll
    for (int ks = 0; ks < 2; ++ks)
      ap[ks] = *(const bf16x8*)&sP[h][l15 * 64 + swzi(l15, ks * 32 + kg)];
    f32x4 accO[4];
#pragma unroll
    for (int n = 0; n < 4; ++n) accO[n] = zf;
#pragma unroll
    for (int ks = 0; ks < 2; ++ks)
#pragma unroll
      for (int n = 0; n < 4; ++n)
        accO[n] = MFMA_BF16(ap[ks], bv[n][ks], accO[n]);
#pragma unroll
    for (int n = 0; n < 4; ++n) {
#pragma unroll
      for (int r = 0; r < 4; ++r) {
        const int row = MOFF[mt] + r4 + r;
        O[(wbase + row) * 512 + h * 64 + n * 16 + l15] = (__bf16)accO[n][r];
      }
    }
  }
}

// ===========================================================================
// Fallback: round-1 fused kernel (used only if ws_size is too small).
// ===========================================================================
__launch_bounds__(256, 2)
__global__ void swin_attn_fused(const float* __restrict__ x,
                                const __bf16* __restrict__ wqkv_bf,
                                const float* __restrict__ bq_s,
                                const __bf16* __restrict__ wproj_bf,
                                const float* __restrict__ bproj,
                                float* __restrict__ out) {
  __shared__ __align__(16) __bf16 s_xw[49 * 512];
  __shared__ __align__(16) __bf16 s_q [49 * 64];
  __shared__ __align__(16) __bf16 s_k [49 * 64];
  __shared__ __align__(16) __bf16 s_vT[64 * 64];
  __shared__ __align__(16) __bf16 s_p [49 * 64];

  const int tid  = threadIdx.x;
  const int lane = tid & 63;
  const int wv   = tid >> 6;
  const int l15  = lane & 15;
  const int kg   = (lane >> 4) * 8;
  const int r4   = (lane >> 4) * 4;
  const int blk = blockIdx.x;
  const int b   = blk >> 10;
  const int wi  = blk & 1023;
  const int MOFF[4] = {0, 16, 32, 33};
  const float NEG_INF = -__builtin_inff();

  for (int i = tid; i < 64 * 64; i += 256) s_vT[i] = (__bf16)0.0f;
  const float* xwin = x + ((size_t)b * 50176 + (size_t)wi) * 512;
  for (int idx = tid; idx < 49 * 128; idx += 256) {
    const int row = idx >> 7;
    const int c4  = (idx & 127) * 4;
    const float4 v = *(const float4*)(xwin + (size_t)row * (1024 * 512) + c4);
    bf16x4 t;
    t.x = (__bf16)v.x; t.y = (__bf16)v.y; t.z = (__bf16)v.z; t.w = (__bf16)v.w;
    *(bf16x4*)&s_xw[row * 512 + swzi(row, c4)] = t;
  }
  f32x4 accF[4][8];
  const f32x4 zf = {0.f, 0.f, 0.f, 0.f};
#pragma unroll
  for (int m = 0; m < 4; ++m)
#pragma unroll
    for (int n = 0; n < 8; ++n) accF[m][n] = zf;
  __syncthreads();

  for (int h = 0; h < 8; ++h) {
    f32x4 accA[4][3];
#pragma unroll
    for (int m = 0; m < 4; ++m)
#pragma unroll
      for (int n = 0; n < 3; ++n) accA[m][n] = zf;
    const __bf16* pB[3];
    float biasv[3];
#pragma unroll
    for (int nt = 0; nt < 3; ++nt) {
      const int c  = wv * 48 + nt * 16 + l15;
      const int wr = (c < 64) ? (h * 64 + c)
                   : (c < 128) ? (512 + h * 64 + (c - 64))
                               : (1024 + h * 64 + (c - 128));
      pB[nt]    = wqkv_bf + (size_t)wr * 512 + kg;
      biasv[nt] = bq_s[wr];
    }
#pragma unroll
    for (int ks = 0; ks < 16; ++ks) {
      bf16x8 a[4], bb[3];
#pragma unroll
      for (int mt = 0; mt < 4; ++mt) {
        const int row = MOFF[mt] + l15;
        a[mt] = *(const bf16x8*)&s_xw[row * 512 + swzi(row, ks * 32 + kg)];
      }
#pragma unroll
      for (int nt = 0; nt < 3; ++nt) bb[nt] = *(const bf16x8*)(pB[nt] + ks * 32);
#pragma unroll
      for (int mt = 0; mt < 4; ++mt)
#pragma unroll
        for (int nt = 0; nt < 3; ++nt)
          accA[mt][nt] = MFMA_BF16(a[mt], bb[nt], accA[mt][nt]);
    }
#pragma unroll
    for (int nt = 0; nt < 3; ++nt) {
      const int c = wv * 48 + nt * 16 + l15;
#pragma unroll
      for (int mt = 0; mt < 4; ++mt) {
#pragma unroll
        for (int r = 0; r < 4; ++r) {
          const int row = MOFF[mt] + r4 + r;
          const __bf16 bvv = (__bf16)(accA[mt][nt][r] + biasv[nt]);
          if (c < 64)       s_q[row * 64 + swzi(row, c)] = bvv;
          else if (c < 128) s_k[row * 64 + swzi(row, c - 64)] = bvv;
          else {
            const int vr = c - 128;
            s_vT[vr * 64 + swzi(vr, row)] = bvv;
          }
        }
      }
    }
    __syncthreads();

    const int R = MOFF[wv];
    bf16x8 aq[2], bkf[4][2];
#pragma unroll
    for (int ks2 = 0; ks2 < 2; ++ks2) {
      const int row = R + l15;
      aq[ks2] = *(const bf16x8*)&s_q[row * 64 + swzi(row, ks2 * 32 + kg)];
    }
#pragma unroll
    for (int nt = 0; nt < 4; ++nt) {
      const int row = MOFF[nt] + l15;
#pragma unroll
      for (int ks2 = 0; ks2 < 2; ++ks2)
        bkf[nt][ks2] = *(const bf16x8*)&s_k[row * 64 + swzi(row, ks2 * 32 + kg)];
    }
    f32x4 accS[4];
#pragma unroll
    for (int n = 0; n < 4; ++n) accS[n] = zf;
#pragma unroll
    for (int ks2 = 0; ks2 < 2; ++ks2)
#pragma unroll
      for (int nt = 0; nt < 4; ++nt)
        accS[nt] = MFMA_BF16(aq[ks2], bkf[nt][ks2], accS[nt]);
#pragma unroll
    for (int r = 0; r < 4; ++r) {
      const int row = R + r4 + r;
      const float sv0 = accS[0][r];
      const float sv1 = accS[1][r];
      const float sv2 = accS[2][r];
      const float sv3 = (l15 == 15) ? accS[3][r] : NEG_INF;
      float m = fmaxf(fmaxf(sv0, sv1), fmaxf(sv2, sv3));
      m = fmaxf(m, __shfl_xor(m, 1));
      m = fmaxf(m, __shfl_xor(m, 2));
      m = fmaxf(m, __shfl_xor(m, 4));
      m = fmaxf(m, __shfl_xor(m, 8));
      const float e0 = __expf(sv0 - m);
      const float e1 = __expf(sv1 - m);
      const float e2 = __expf(sv2 - m);
      const float e3 = __expf(sv3 - m);
      float s = e0 + e1 + e2 + e3;
      s += __shfl_xor(s, 1);
      s += __shfl_xor(s, 2);
      s += __shfl_xor(s, 4);
      s += __shfl_xor(s, 8);
      const float inv = 1.0f / s;
      s_p[row * 64 + swzi(row, 0  + l15)] = (__bf16)(e0 * inv);
      s_p[row * 64 + swzi(row, 16 + l15)] = (__bf16)(e1 * inv);
      s_p[row * 64 + swzi(row, 32 + l15)] = (__bf16)(e2 * inv);
      if (l15 == 15) s_p[row * 64 + swzi(row, 48)] = (__bf16)(e3 * inv);
      if (l15 < 15)  s_p[row * 64 + swzi(row, 49 + l15)] = (__bf16)0.0f;
    }
    bf16x8 ap[2], bv2[4][2];
#pragma unroll
    for (int ks2 = 0; ks2 < 2; ++ks2) {
      const int row = R + l15;
      ap[ks2] = *(const bf16x8*)&s_p[row * 64 + swzi(row, ks2 * 32 + kg)];
    }
#pragma unroll
    for (int nt = 0; nt < 4; ++nt) {
      const int row = nt * 16 + l15;
#pragma unroll
      for (int ks2 = 0; ks2 < 2; ++ks2)
        bv2[nt][ks2] = *(const bf16x8*)&s_vT[row * 64 + swzi(row, ks2 * 32 + kg)];
    }
    __syncthreads();
    f32x4 accO[4];
#pragma unroll
    for (int n = 0; n < 4; ++n) accO[n] = zf;
#pragma unroll
    for (int ks2 = 0; ks2 < 2; ++ks2)
#pragma unroll
      for (int nt = 0; nt < 4; ++nt)
        accO[nt] = MFMA_BF16(ap[ks2], bv2[nt][ks2], accO[nt]);
#pragma unroll
    for (int nt = 0; nt < 4; ++nt) {
#pragma unroll
      for (int r = 0; r < 4; ++r) {
        const int row = R + r4 + r;
        s_p[row * 64 + swzi(row, nt * 16 + l15)] = (__bf16)accO[nt][r];
      }
    }
    __syncthreads();
#pragma unroll
    for (int ks2 = 0; ks2 < 2; ++ks2) {
      bf16x8 ao[4], bw[8];
#pragma unroll
      for (int mt = 0; mt < 4; ++mt) {
        const int row = MOFF[mt] + l15;
        ao[mt] = *(const bf16x8*)&s_p[row * 64 + swzi(row, ks2 * 32 + kg)];
      }
#pragma unroll
      for (int nt = 0; nt < 8; ++nt) {
        const int cc = wv * 128 + nt * 16 + l15;
        bw[nt] = *(const bf16x8*)(wproj_bf + (size_t)cc * 512 + h * 64 + ks2 * 32 + kg);
      }
#pragma unroll
      for (int mt = 0; mt < 4; ++mt)
#pragma unroll
        for (int nt = 0; nt < 8; ++nt)
          accF[mt][nt] = MFMA_BF16(ao[mt], bw[nt], accF[mt][nt]);
    }
  }
#pragma unroll
  for (int nt = 0; nt < 8; ++nt) {
    const int cc = wv * 128 + nt * 16 + l15;
    const float bp = bproj[cc];
#pragma unroll
    for (int mt = 0; mt < 4; ++mt) {
#pragma unroll
      for (int r = 0; r < 4; ++r) {
        const int row = MOFF[mt] + r4 + r;
        if (mt < 3 || (r4 + r) == 15) {
          out[((size_t)b * 50176 + (size_t)row * 1024 + (size_t)wi) * 512 + cc] =
              accF[mt][nt][r] + bp;
        }
      }
    }
  }
}

// ---------------------------------------------------------------------------
extern "C" void kernel_launch(void* const* d_in, const int* in_sizes, int n_in,
                              void* d_out, int out_size, void* d_ws, size_t ws_size,
                              hipStream_t stream) {
  const float* x      = (const float*)d_in[0];
  const float* w_qkv  = (const float*)d_in[1];
  const float* b_qkv  = (const float*)d_in[2];
  const float* w_proj = (const float*)d_in[3];
  const float* b_proj = (const float*)d_in[4];
  float* outp = (float*)d_out;

  const size_t QKV_E = (size_t)200704 * 1536;
  const size_t O_E   = (size_t)200704 * 512;
  const size_t NEED  = (QKV_E + O_E + 786432 + 262144) * 2 + 1536 * 4;

  if (ws_size >= NEED) {
    __bf16* qkv      = (__bf16*)d_ws;
    __bf16* Obuf     = qkv + QKV_E;      // holds x_bf16 first, then attn output
    __bf16* wqkv_bf  = Obuf + O_E;
    __bf16* wproj_bf = wqkv_bf + 786432;
    float*  bq_s     = (float*)(wproj_bf + 262144);

    prep_all<<<2048, 256, 0, stream>>>(x, w_qkv, b_qkv, w_proj,
                                       Obuf, wqkv_bf, wproj_bf, bq_s);
    // QKV: M=200704 (784 tiles), N=1536 (6 tiles)
    gemm256<false, false><<<784 * 6, 512, 0, stream>>>(Obuf, wqkv_bf, bq_s, qkv, 784, 6);
    attn_win<<<4096, 512, 0, stream>>>(qkv, Obuf);   // overwrites x_bf16
    // proj: M=200704 (784 tiles), N=512 (2 tiles); permuted store to token-major
    gemm256<true, true><<<784 * 2, 512, 0, stream>>>(Obuf, wproj_bf, b_proj, outp, 784, 2);
  } else {
    __bf16* wqkv_bf  = (__bf16*)d_ws;
    __bf16* wproj_bf = wqkv_bf + 1536 * 512;
    float*  bq_s     = (float*)(wproj_bf + 512 * 512);
    prep_weights<<<1024, 256, 0, stream>>>(w_qkv, b_qkv, w_proj, wqkv_bf, wproj_bf, bq_s);
    swin_attn_fused<<<4096, 256, 0, stream>>>(x, wqkv_bf, bq_s, wproj_bf, b_proj, outp);
  }
}

// Round 15
// 946.722 us; speedup vs baseline: 1.1916x; 1.0372x over previous
//
#include <hip/hip_runtime.h>
#include <cstdint>
#include <cstddef>

// ---------------------------------------------------------------------------
// ShuffleWindowAttention, MI355X (gfx950)
// B=4, N=50176, C=512, WS=49, w=1024 windows/batch, NH=8, hd=64
// Pipeline (window-major intermediates):
//   prep_all (weights->bf16 + x fp32->bf16 window-major gather, one kernel)
//   -> QKV GEMM (256^2, BK=64, R9 skeleton + EARLY-STAGE placement)
//   -> windowed attention (vswz, conflict-free) -> proj GEMM (same template).
// R15 = R14 with GEMM staging shifted earlier: all 4 half-tiles of t+1 are
// issued in ph0-ph2 of tile t (legal: end-of-tile barrier of t-1 retired all
// reads of nxt), so every load gets >=2 phases of latency cover; the tile-top
// wait becomes vmcnt(0) at a naturally-empty point. Sync skeleton unchanged.
// GEMM ledger: R5 456 | R6 524 | R9 417* | R10 487 | R13 520 | R15 this.
// ---------------------------------------------------------------------------

typedef __bf16 bf16x8 __attribute__((ext_vector_type(8)));
typedef __bf16 bf16x4 __attribute__((ext_vector_type(4)));
typedef float  f32x4  __attribute__((ext_vector_type(4)));

#define MFMA_BF16(a, b, c) __builtin_amdgcn_mfma_f32_16x16x32_bf16((a), (b), (c), 0, 0, 0)

static __device__ __forceinline__ int swzi(int row, int col) {
  return col ^ ((row & 7) << 3);   // sP swizzle (128B rows)
}
static __device__ __forceinline__ int vswz(int n, int k) {
  return k ^ (((n ^ (n >> 3)) & 7) << 3);
}

typedef __attribute__((address_space(1))) const void gconst_t;
typedef __attribute__((address_space(3))) void lds_t;
static __device__ __forceinline__ void gload16(const void* g, void* l) {
  __builtin_amdgcn_global_load_lds((gconst_t*)g, (lds_t*)l, 16, 0, 0);
}

#define WAITV0()   asm volatile("s_waitcnt vmcnt(0)" ::: "memory")

// window-major row -> token row
static __device__ __forceinline__ int wm2tok(int m) {
  const int b   = m / 50176;
  const int rem = m - b * 50176;
  const int wi  = rem / 49;
  const int s   = rem - wi * 49;
  return b * 50176 + s * 1024 + wi;
}

// ---------------------------------------------------------------------------
// Weight prep (fallback path): fp32 -> bf16, 0.125 scale folded into Q.
// ---------------------------------------------------------------------------
__global__ void prep_weights(const float* __restrict__ wqkv,
                             const float* __restrict__ bqkv,
                             const float* __restrict__ wproj,
                             __bf16* __restrict__ wqkv_bf,
                             __bf16* __restrict__ wproj_bf,
                             float* __restrict__ bq_s) {
  const int stride = gridDim.x * blockDim.x;
  const int t0 = blockIdx.x * blockDim.x + threadIdx.x;
  for (int i = t0; i < 1536 * 512; i += stride) {
    float v = wqkv[i];
    if (i < 512 * 512) v *= 0.125f;
    wqkv_bf[i] = (__bf16)v;
  }
  for (int i = t0; i < 512 * 512; i += stride) wproj_bf[i] = (__bf16)wproj[i];
  for (int i = t0; i < 1536; i += stride)      bq_s[i] = (i < 512 ? 0.125f : 1.0f) * bqkv[i];
}

// Combined prep: weights AND x gather/convert (main path, one launch).
__global__ void prep_all(const float* __restrict__ x,
                         const float* __restrict__ wqkv,
                         const float* __restrict__ bqkv,
                         const float* __restrict__ wproj,
                         __bf16* __restrict__ xb,
                         __bf16* __restrict__ wqkv_bf,
                         __bf16* __restrict__ wproj_bf,
                         float* __restrict__ bq_s) {
  const size_t gstride = (size_t)gridDim.x * blockDim.x;
  const size_t g0 = (size_t)blockIdx.x * blockDim.x + threadIdx.x;

  for (size_t i = g0; i < 1536 * 512; i += gstride) {
    float v = wqkv[i];
    if (i < 512 * 512) v *= 0.125f;
    wqkv_bf[i] = (__bf16)v;
  }
  for (size_t i = g0; i < 512 * 512; i += gstride) wproj_bf[i] = (__bf16)wproj[i];
  for (size_t i = g0; i < 1536; i += gstride)
    bq_s[i] = (i < 512 ? 0.125f : 1.0f) * bqkv[i];

  const size_t total = (size_t)200704 * 64;
  for (size_t i = g0; i < total; i += gstride) {
    const int m  = (int)(i >> 6);
    const int c8 = ((int)i & 63) * 8;
    const size_t t = (size_t)wm2tok(m);
    const float4 a = *(const float4*)(x + t * 512 + c8);
    const float4 b = *(const float4*)(x + t * 512 + c8 + 4);
    bf16x8 v;
    v[0] = (__bf16)a.x; v[1] = (__bf16)a.y; v[2] = (__bf16)a.z; v[3] = (__bf16)a.w;
    v[4] = (__bf16)b.x; v[5] = (__bf16)b.y; v[6] = (__bf16)b.z; v[7] = (__bf16)b.w;
    *(bf16x8*)(xb + i * 8) = v;
  }
}

// ---------------------------------------------------------------------------
// 256x256-tile GEMM: R9 sync skeleton, EARLY staging (R15):
//   top:   vmcnt(0) [load queue designed empty] ; s_barrier ; sched_barrier
//   ph0:   LDB0+LDA00 ; stage Ah0,Ah1(t+1) ; MM
//   ph1:   LDA10 ; stage Bh0(t+1) ; MM
//   ph2:   LDB1+LDA01 ; stage Bh1(t+1) ; MM
//   ph3:   LDA11 ; MM
//   end:   sched_barrier ; s_barrier
// Every t+1 load gets >=2 phases + 2 barriers of HBM-latency cover.
// ---------------------------------------------------------------------------
template<bool OUT_F32, bool PERM_OUT>
__launch_bounds__(512, 2)
__global__ void gemm256(const __bf16* __restrict__ Ab,   // [M][512]
                        const __bf16* __restrict__ Bw,   // [N][512]
                        const float* __restrict__ bias,  // [N]
                        void* __restrict__ Cv,
                        int Mtiles, int Ntiles) {
  __shared__ __align__(16) __bf16 sA[2][256 * 64];
  __shared__ __align__(16) __bf16 sB[2][256 * 64];

  const int tid  = threadIdx.x;
  const int lane = tid & 63;
  const int l15  = lane & 15;
  const int kgc  = (lane >> 4) & 3;
  const int r4   = kgc * 4;
  const int wv   = tid >> 6;
  const int wm   = wv >> 2, wn = wv & 3;

  const int nwg = Mtiles * Ntiles;
  const int cpx = nwg >> 3;
  const int wg  = (blockIdx.x & 7) * cpx + (blockIdx.x >> 3);
  const int mt  = wg / Ntiles;
  const int nt  = wg % Ntiles;
  const size_t m0 = (size_t)mt * 256;
  const int    n0 = nt * 256;

  const int srow   = tid >> 3;
  const int schunk = (tid & 7) ^ (srow & 7);

  f32x4 acc[8][4];
  const f32x4 zf = {0.f, 0.f, 0.f, 0.f};
#pragma unroll
  for (int i = 0; i < 8; ++i)
#pragma unroll
    for (int j = 0; j < 4; ++j) acc[i][j] = zf;

  auto STAGE_HALF = [&](int bufi, int kt, int mat, int h) {
    const size_t kof = (size_t)kt * 64 + schunk * 8;
    const __bf16* src = mat ? Bw : Ab;
    const size_t base0 = mat ? (size_t)n0 : m0;
    __bf16* dst = (mat ? &sB[bufi][0] : &sA[bufi][0]) + h * 8192 + tid * 8;
#pragma unroll
    for (int j = 0; j < 2; ++j)
      gload16(src + (base0 + (size_t)(h * 128 + j * 64 + srow)) * 512 + kof,
              dst + j * 4096);
  };

  auto LDB = [&](int bufi, int ks, bf16x8* bfrag) {
#pragma unroll
    for (int n = 0; n < 4; ++n) {
      const int r = wn * 64 + n * 16 + l15;
      bfrag[n] = *(const bf16x8*)&sB[bufi][r * 64 + (((ks * 4 + kgc) ^ (r & 7)) * 8)];
    }
  };
  auto LDA = [&](int bufi, int mh, int ks, bf16x8* afrag) {
#pragma unroll
    for (int m2 = 0; m2 < 4; ++m2) {
      const int r = wm * 128 + mh * 64 + m2 * 16 + l15;
      afrag[m2] = *(const bf16x8*)&sA[bufi][r * 64 + (((ks * 4 + kgc) ^ (r & 7)) * 8)];
    }
  };
  auto MM = [&](int mh, const bf16x8* afrag, const bf16x8* bfrag) {
    __builtin_amdgcn_s_setprio(1);
#pragma unroll
    for (int m2 = 0; m2 < 4; ++m2)
#pragma unroll
      for (int n = 0; n < 4; ++n)
        acc[mh * 4 + m2][n] = MFMA_BF16(afrag[m2], bfrag[n], acc[mh * 4 + m2][n]);
    __builtin_amdgcn_s_setprio(0);
  };

  // prologue: all 4 half-tiles of K-tile 0 -> buf 0 (8 loads in flight)
  STAGE_HALF(0, 0, 0, 0); STAGE_HALF(0, 0, 0, 1);
  STAGE_HALF(0, 0, 1, 0); STAGE_HALF(0, 0, 1, 1);

  int buf = 0;
  for (int t = 0; t < 8; ++t) {
    const int nxt = buf ^ 1;
    // ---- tile top: drain own tile-t loads (queue designed empty here) ----
    WAITV0();
    __builtin_amdgcn_s_barrier();
    __builtin_amdgcn_sched_barrier(0);

    bf16x8 b0[4], b1[4], a[4];
    // ph0: (ks0, mh0)  + stage Ah0,Ah1(t+1)  [nxt reads retired since t-1 end]
    LDB(buf, 0, b0);
    LDA(buf, 0, 0, a);
    if (t < 7) { STAGE_HALF(nxt, t + 1, 0, 0); STAGE_HALF(nxt, t + 1, 0, 1); }
    MM(0, a, b0);
    // ph1: (ks0, mh1)  + stage Bh0(t+1)
    LDA(buf, 1, 0, a);
    if (t < 7) STAGE_HALF(nxt, t + 1, 1, 0);
    MM(1, a, b0);
    // ph2: (ks1, mh0)  + stage Bh1(t+1)
    LDB(buf, 1, b1);
    LDA(buf, 0, 1, a);
    if (t < 7) STAGE_HALF(nxt, t + 1, 1, 1);
    MM(0, a, b1);
    // ph3: (ks1, mh1)
    LDA(buf, 1, 1, a);
    MM(1, a, b1);

    // end-of-tile barrier: all waves done reading buf
    __builtin_amdgcn_sched_barrier(0);
    __builtin_amdgcn_s_barrier();
    buf = nxt;
  }

  const int Nld = Ntiles * 256;
#pragma unroll
  for (int m = 0; m < 8; ++m) {
#pragma unroll
    for (int r = 0; r < 4; ++r) {
      const int row = (int)m0 + wm * 128 + m * 16 + r4 + r;
      const size_t orow = PERM_OUT ? (size_t)wm2tok(row) : (size_t)row;
#pragma unroll
      for (int n = 0; n < 4; ++n) {
        const int col = n0 + wn * 64 + n * 16 + l15;
        const float v = acc[m][n][r] + bias[col];
        if (OUT_F32) ((float*)Cv)[orow * (size_t)Nld + col] = v;
        else         ((__bf16*)Cv)[orow * (size_t)Nld + col] = (__bf16)v;
      }
    }
  }
}

// ---------------------------------------------------------------------------
// Windowed attention (R12 verbatim): vswz double-XOR, conflict-free.
// ---------------------------------------------------------------------------
__launch_bounds__(512)
__global__ void attn_win(const __bf16* __restrict__ qkv, __bf16* __restrict__ O) {
  __shared__ __align__(16) __bf16 vT[8 * 64 * 64];
  __shared__ __align__(16) __bf16 sP[8][16 * 64];

  const int tid  = threadIdx.x;
  const int lane = tid & 63;
  const int h    = tid >> 6;
  const int l15  = lane & 15;
  const int kg   = ((lane >> 4) & 3) * 8;
  const int r4   = ((lane >> 4) & 3) * 4;

  const size_t wbase = (size_t)blockIdx.x * 49;

  const int MOFF[4] = {0, 16, 32, 33};
  const float NEG_INF = -__builtin_inff();

  bf16x8 aq[4][2], bk[4][2];
#pragma unroll
  for (int mt = 0; mt < 4; ++mt) {
    const size_t tok = wbase + (size_t)(MOFF[mt] + l15);
#pragma unroll
    for (int ks = 0; ks < 2; ++ks) {
      aq[mt][ks] = *(const bf16x8*)(qkv + tok * 1536 +       h * 64 + ks * 32 + kg);
      bk[mt][ks] = *(const bf16x8*)(qkv + tok * 1536 + 512 + h * 64 + ks * 32 + kg);
    }
  }

  for (int i = tid; i < 8 * 64 * 16; i += 512) {
    const int k = 48 + (i & 15);
    if (k != 48) {
      const int n  = (i >> 4) & 63;
      const int hh = i >> 10;
      vT[hh * 4096 + n * 64 + vswz(n, k)] = (__bf16)0.0f;
    }
  }
  for (int i = tid; i < 49 * 64; i += 512) {
    const int s  = i >> 6;
    const int c8 = (i & 63) * 8;
    bf16x8 v8 = *(const bf16x8*)(qkv + (wbase + s) * 1536 + 1024 + c8);
    const int hh = c8 >> 6;
#pragma unroll
    for (int j = 0; j < 8; ++j) {
      const int n = (c8 & 63) + j;
      vT[hh * 4096 + n * 64 + vswz(n, s)] = v8[j];
    }
  }
  __syncthreads();

  bf16x8 bv[4][2];
#pragma unroll
  for (int ntv = 0; ntv < 4; ++ntv) {
    const int n = ntv * 16 + l15;
#pragma unroll
    for (int ks = 0; ks < 2; ++ks)
      bv[ntv][ks] = *(const bf16x8*)&vT[h * 4096 + n * 64 + vswz(n, ks * 32 + kg)];
  }

  f32x4 accS[4][4];
  const f32x4 zf = {0.f, 0.f, 0.f, 0.f};
#pragma unroll
  for (int m = 0; m < 4; ++m)
#pragma unroll
    for (int n = 0; n < 4; ++n) accS[m][n] = zf;
#pragma unroll
  for (int ks = 0; ks < 2; ++ks)
#pragma unroll
    for (int m = 0; m < 4; ++m)
#pragma unroll
      for (int n = 0; n < 4; ++n)
        accS[m][n] = MFMA_BF16(aq[m][ks], bk[n][ks], accS[m][n]);

#pragma unroll
  for (int mt = 0; mt < 4; ++mt) {
#pragma unroll
    for (int r = 0; r < 4; ++r) {
      const int prow = r4 + r;
      const float sv0 = accS[mt][0][r];
      const float sv1 = accS[mt][1][r];
      const float sv2 = accS[mt][2][r];
      const float sv3 = (l15 == 15) ? accS[mt][3][r] : NEG_INF;
      float mx = fmaxf(fmaxf(sv0, sv1), fmaxf(sv2, sv3));
      mx = fmaxf(mx, __shfl_xor(mx, 1));
      mx = fmaxf(mx, __shfl_xor(mx, 2));
      mx = fmaxf(mx, __shfl_xor(mx, 4));
      mx = fmaxf(mx, __shfl_xor(mx, 8));
      const float e0 = __expf(sv0 - mx);
      const float e1 = __expf(sv1 - mx);
      const float e2 = __expf(sv2 - mx);
      const float e3 = __expf(sv3 - mx);
      float sum = e0 + e1 + e2 + e3;
      sum += __shfl_xor(sum, 1);
      sum += __shfl_xor(sum, 2);
      sum += __shfl_xor(sum, 4);
      sum += __shfl_xor(sum, 8);
      const float inv = 1.0f / sum;
      sP[h][prow * 64 + swzi(prow, 0  + l15)] = (__bf16)(e0 * inv);
      sP[h][prow * 64 + swzi(prow, 16 + l15)] = (__bf16)(e1 * inv);
      sP[h][prow * 64 + swzi(prow, 32 + l15)] = (__bf16)(e2 * inv);
      if (l15 == 15) sP[h][prow * 64 + swzi(prow, 48)] = (__bf16)(e3 * inv);
      if (l15 < 15)  sP[h][prow * 64 + swzi(prow, 49 + l15)] = (__bf16)0.0f;
    }
    bf16x8 ap[2];
#pragma unroll
    for (int ks = 0; ks < 2; ++ks)
      ap[ks] = *(const bf16x8*)&sP[h][l15 * 64 + swzi(l15, ks * 32 + kg)];
    f32x4 accO[4];
#pragma unroll
    for (int n = 0; n < 4; ++n) accO[n] = zf;
#pragma unroll
    for (int ks = 0; ks < 2; ++ks)
#pragma unroll
      for (int n = 0; n < 4; ++n)
        accO[n] = MFMA_BF16(ap[ks], bv[n][ks], accO[n]);
#pragma unroll
    for (int n = 0; n < 4; ++n) {
#pragma unroll
      for (int r = 0; r < 4; ++r) {
        const int row = MOFF[mt] + r4 + r;
        O[(wbase + row) * 512 + h * 64 + n * 16 + l15] = (__bf16)accO[n][r];
      }
    }
  }
}

// ===========================================================================
// Fallback: round-1 fused kernel (used only if ws_size is too small).
// ===========================================================================
__launch_bounds__(256, 2)
__global__ void swin_attn_fused(const float* __restrict__ x,
                                const __bf16* __restrict__ wqkv_bf,
                                const float* __restrict__ bq_s,
                                const __bf16* __restrict__ wproj_bf,
                                const float* __restrict__ bproj,
                                float* __restrict__ out) {
  __shared__ __align__(16) __bf16 s_xw[49 * 512];
  __shared__ __align__(16) __bf16 s_q [49 * 64];
  __shared__ __align__(16) __bf16 s_k [49 * 64];
  __shared__ __align__(16) __bf16 s_vT[64 * 64];
  __shared__ __align__(16) __bf16 s_p [49 * 64];

  const int tid  = threadIdx.x;
  const int lane = tid & 63;
  const int wv   = tid >> 6;
  const int l15  = lane & 15;
  const int kg   = (lane >> 4) * 8;
  const int r4   = (lane >> 4) * 4;
  const int blk = blockIdx.x;
  const int b   = blk >> 10;
  const int wi  = blk & 1023;
  const int MOFF[4] = {0, 16, 32, 33};
  const float NEG_INF = -__builtin_inff();

  for (int i = tid; i < 64 * 64; i += 256) s_vT[i] = (__bf16)0.0f;
  const float* xwin = x + ((size_t)b * 50176 + (size_t)wi) * 512;
  for (int idx = tid; idx < 49 * 128; idx += 256) {
    const int row = idx >> 7;
    const int c4  = (idx & 127) * 4;
    const float4 v = *(const float4*)(xwin + (size_t)row * (1024 * 512) + c4);
    bf16x4 t;
    t.x = (__bf16)v.x; t.y = (__bf16)v.y; t.z = (__bf16)v.z; t.w = (__bf16)v.w;
    *(bf16x4*)&s_xw[row * 512 + swzi(row, c4)] = t;
  }
  f32x4 accF[4][8];
  const f32x4 zf = {0.f, 0.f, 0.f, 0.f};
#pragma unroll
  for (int m = 0; m < 4; ++m)
#pragma unroll
    for (int n = 0; n < 8; ++n) accF[m][n] = zf;
  __syncthreads();

  for (int h = 0; h < 8; ++h) {
    f32x4 accA[4][3];
#pragma unroll
    for (int m = 0; m < 4; ++m)
#pragma unroll
      for (int n = 0; n < 3; ++n) accA[m][n] = zf;
    const __bf16* pB[3];
    float biasv[3];
#pragma unroll
    for (int nt = 0; nt < 3; ++nt) {
      const int c  = wv * 48 + nt * 16 + l15;
      const int wr = (c < 64) ? (h * 64 + c)
                   : (c < 128) ? (512 + h * 64 + (c - 64))
                               : (1024 + h * 64 + (c - 128));
      pB[nt]    = wqkv_bf + (size_t)wr * 512 + kg;
      biasv[nt] = bq_s[wr];
    }
#pragma unroll
    for (int ks = 0; ks < 16; ++ks) {
      bf16x8 a[4], bb[3];
#pragma unroll
      for (int mt = 0; mt < 4; ++mt) {
        const int row = MOFF[mt] + l15;
        a[mt] = *(const bf16x8*)&s_xw[row * 512 + swzi(row, ks * 32 + kg)];
      }
#pragma unroll
      for (int nt = 0; nt < 3; ++nt) bb[nt] = *(const bf16x8*)(pB[nt] + ks * 32);
#pragma unroll
      for (int mt = 0; mt < 4; ++mt)
#pragma unroll
        for (int nt = 0; nt < 3; ++nt)
          accA[mt][nt] = MFMA_BF16(a[mt], bb[nt], accA[mt][nt]);
    }
#pragma unroll
    for (int nt = 0; nt < 3; ++nt) {
      const int c = wv * 48 + nt * 16 + l15;
#pragma unroll
      for (int mt = 0; mt < 4; ++mt) {
#pragma unroll
        for (int r = 0; r < 4; ++r) {
          const int row = MOFF[mt] + r4 + r;
          const __bf16 bvv = (__bf16)(accA[mt][nt][r] + biasv[nt]);
          if (c < 64)       s_q[row * 64 + swzi(row, c)] = bvv;
          else if (c < 128) s_k[row * 64 + swzi(row, c - 64)] = bvv;
          else {
            const int vr = c - 128;
            s_vT[vr * 64 + swzi(vr, row)] = bvv;
          }
        }
      }
    }
    __syncthreads();

    const int R = MOFF[wv];
    bf16x8 aq[2], bkf[4][2];
#pragma unroll
    for (int ks2 = 0; ks2 < 2; ++ks2) {
      const int row = R + l15;
      aq[ks2] = *(const bf16x8*)&s_q[row * 64 + swzi(row, ks2 * 32 + kg)];
    }
#pragma unroll
    for (int nt = 0; nt < 4; ++nt) {
      const int row = MOFF[nt] + l15;
#pragma unroll
      for (int ks2 = 0; ks2 < 2; ++ks2)
        bkf[nt][ks2] = *(const bf16x8*)&s_k[row * 64 + swzi(row, ks2 * 32 + kg)];
    }
    f32x4 accS[4];
#pragma unroll
    for (int n = 0; n < 4; ++n) accS[n] = zf;
#pragma unroll
    for (int ks2 = 0; ks2 < 2; ++ks2)
#pragma unroll
      for (int nt = 0; nt < 4; ++nt)
        accS[nt] = MFMA_BF16(aq[ks2], bkf[nt][ks2], accS[nt]);
#pragma unroll
    for (int r = 0; r < 4; ++r) {
      const int row = R + r4 + r;
      const float sv0 = accS[0][r];
      const float sv1 = accS[1][r];
      const float sv2 = accS[2][r];
      const float sv3 = (l15 == 15) ? accS[3][r] : NEG_INF;
      float m = fmaxf(fmaxf(sv0, sv1), fmaxf(sv2, sv3));
      m = fmaxf(m, __shfl_xor(m, 1));
      m = fmaxf(m, __shfl_xor(m, 2));
      m = fmaxf(m, __shfl_xor(m, 4));
      m = fmaxf(m, __shfl_xor(m, 8));
      const float e0 = __expf(sv0 - m);
      const float e1 = __expf(sv1 - m);
      const float e2 = __expf(sv2 - m);
      const float e3 = __expf(sv3 - m);
      float s = e0 + e1 + e2 + e3;
      s += __shfl_xor(s, 1);
      s += __shfl_xor(s, 2);
      s += __shfl_xor(s, 4);
      s += __shfl_xor(s, 8);
      const float inv = 1.0f / s;
      s_p[row * 64 + swzi(row, 0  + l15)] = (__bf16)(e0 * inv);
      s_p[row * 64 + swzi(row, 16 + l15)] = (__bf16)(e1 * inv);
      s_p[row * 64 + swzi(row, 32 + l15)] = (__bf16)(e2 * inv);
      if (l15 == 15) s_p[row * 64 + swzi(row, 48)] = (__bf16)(e3 * inv);
      if (l15 < 15)  s_p[row * 64 + swzi(row, 49 + l15)] = (__bf16)0.0f;
    }
    bf16x8 ap[2], bv2[4][2];
#pragma unroll
    for (int ks2 = 0; ks2 < 2; ++ks2) {
      const int row = R + l15;
      ap[ks2] = *(const bf16x8*)&s_p[row * 64 + swzi(row, ks2 * 32 + kg)];
    }
#pragma unroll
    for (int nt = 0; nt < 4; ++nt) {
      const int row = nt * 16 + l15;
#pragma unroll
      for (int ks2 = 0; ks2 < 2; ++ks2)
        bv2[nt][ks2] = *(const bf16x8*)&s_vT[row * 64 + swzi(row, ks2 * 32 + kg)];
    }
    __syncthreads();
    f32x4 accO[4];
#pragma unroll
    for (int n = 0; n < 4; ++n) accO[n] = zf;
#pragma unroll
    for (int ks2 = 0; ks2 < 2; ++ks2)
#pragma unroll
      for (int nt = 0; nt < 4; ++nt)
        accO[nt] = MFMA_BF16(ap[ks2], bv2[nt][ks2], accO[nt]);
#pragma unroll
    for (int nt = 0; nt < 4; ++nt) {
#pragma unroll
      for (int r = 0; r < 4; ++r) {
        const int row = R + r4 + r;
        s_p[row * 64 + swzi(row, nt * 16 + l15)] = (__bf16)accO[nt][r];
      }
    }
    __syncthreads();
#pragma unroll
    for (int ks2 = 0; ks2 < 2; ++ks2) {
      bf16x8 ao[4], bw[8];
#pragma unroll
      for (int mt = 0; mt < 4; ++mt) {
        const int row = MOFF[mt] + l15;
        ao[mt] = *(const bf16x8*)&s_p[row * 64 + swzi(row, ks2 * 32 + kg)];
      }
#pragma unroll
      for (int nt = 0; nt < 8; ++nt) {
        const int cc = wv * 128 + nt * 16 + l15;
        bw[nt] = *(const bf16x8*)(wproj_bf + (size_t)cc * 512 + h * 64 + ks2 * 32 + kg);
      }
#pragma unroll
      for (int mt = 0; mt < 4; ++mt)
#pragma unroll
        for (int nt = 0; nt < 8; ++nt)
          accF[mt][nt] = MFMA_BF16(ao[mt], bw[nt], accF[mt][nt]);
    }
  }
#pragma unroll
  for (int nt = 0; nt < 8; ++nt) {
    const int cc = wv * 128 + nt * 16 + l15;
    const float bp = bproj[cc];
#pragma unroll
    for (int mt = 0; mt < 4; ++mt) {
#pragma unroll
      for (int r = 0; r < 4; ++r) {
        const int row = MOFF[mt] + r4 + r;
        if (mt < 3 || (r4 + r) == 15) {
          out[((size_t)b * 50176 + (size_t)row * 1024 + (size_t)wi) * 512 + cc] =
              accF[mt][nt][r] + bp;
        }
      }
    }
  }
}

// ---------------------------------------------------------------------------
extern "C" void kernel_launch(void* const* d_in, const int* in_sizes, int n_in,
                              void* d_out, int out_size, void* d_ws, size_t ws_size,
                              hipStream_t stream) {
  const float* x      = (const float*)d_in[0];
  const float* w_qkv  = (const float*)d_in[1];
  const float* b_qkv  = (const float*)d_in[2];
  const float* w_proj = (const float*)d_in[3];
  const float* b_proj = (const float*)d_in[4];
  float* outp = (float*)d_out;

  const size_t QKV_E = (size_t)200704 * 1536;
  const size_t O_E   = (size_t)200704 * 512;
  const size_t NEED  = (QKV_E + O_E + 786432 + 262144) * 2 + 1536 * 4;

  if (ws_size >= NEED) {
    __bf16* qkv      = (__bf16*)d_ws;
    __bf16* Obuf     = qkv + QKV_E;      // holds x_bf16 first, then attn output
    __bf16* wqkv_bf  = Obuf + O_E;
    __bf16* wproj_bf = wqkv_bf + 786432;
    float*  bq_s     = (float*)(wproj_bf + 262144);

    prep_all<<<2048, 256, 0, stream>>>(x, w_qkv, b_qkv, w_proj,
                                       Obuf, wqkv_bf, wproj_bf, bq_s);
    // QKV: M=200704 (784 tiles), N=1536 (6 tiles)
    gemm256<false, false><<<784 * 6, 512, 0, stream>>>(Obuf, wqkv_bf, bq_s, qkv, 784, 6);
    attn_win<<<4096, 512, 0, stream>>>(qkv, Obuf);   // overwrites x_bf16
    // proj: M=200704 (784 tiles), N=512 (2 tiles); permuted store to token-major
    gemm256<true, true><<<784 * 2, 512, 0, stream>>>(Obuf, wproj_bf, b_proj, outp, 784, 2);
  } else {
    __bf16* wqkv_bf  = (__bf16*)d_ws;
    __bf16* wproj_bf = wqkv_bf + 1536 * 512;
    float*  bq_s     = (float*)(wproj_bf + 512 * 512);
    prep_weights<<<1024, 256, 0, stream>>>(w_qkv, b_qkv, w_proj, wqkv_bf, wproj_bf, bq_s);
    swin_attn_fused<<<4096, 256, 0, stream>>>(x, wqkv_bf, bq_s, wproj_bf, b_proj, outp);
  }
}